// Round 1
// baseline (338.173 us; speedup 1.0000x reference)
//
#include <hip/hip_runtime.h>
#include <hip/hip_bf16.h>

// ---------- types ----------
typedef float f32x4 __attribute__((ext_vector_type(4)));
typedef __bf16 bfx8 __attribute__((ext_vector_type(8)));

#define NTOK 4096
#define NHEAD 8
#define DHEAD 64

__device__ inline f32x4 mfma16(bfx8 a, bfx8 b, f32x4 c) {
    return __builtin_amdgcn_mfma_f32_16x16x32_bf16(a, b, c, 0, 0, 0);
}

// ============================================================
// Kernel 1: QKV projection. X[4096,256] fp32 @ W[256,1536] fp32
//  -> Q[h][n][64] bf16 (×0.125), K[h][n][64] bf16, Vt[h][64][n] bf16
// tile BM=128 BN=128 BK=32, 4 waves (2x2), each wave 64x64 (4x4 frags)
// ============================================================
__global__ __launch_bounds__(256) void gemm_qkv(
    const float* __restrict__ X, const float* __restrict__ W,
    __bf16* __restrict__ Q, __bf16* __restrict__ Kb, __bf16* __restrict__ Vt)
{
    __shared__ __bf16 As[128 * 40];   // [row][k], pad 40 to break bank stride
    __shared__ __bf16 Bs[128 * 40];   // B^T: [col][k]
    const int tid  = threadIdx.x;
    const int lane = tid & 63;
    const int wv   = tid >> 6;
    const int wr   = wv >> 1, wc = wv & 1;
    const int m0 = blockIdx.y * 128;
    const int n0 = blockIdx.x * 128;
    const int l15 = lane & 15, l4 = lane >> 4;

    f32x4 zero = {0.f, 0.f, 0.f, 0.f};
    f32x4 acc[4][4];
#pragma unroll
    for (int i = 0; i < 4; ++i)
#pragma unroll
        for (int j = 0; j < 4; ++j) acc[i][j] = zero;

    for (int k0 = 0; k0 < 256; k0 += 32) {
        __syncthreads();
        // stage A tile: 128 rows x 32 k fp32 -> bf16
#pragma unroll
        for (int rep = 0; rep < 4; ++rep) {
            int idx = rep * 256 + tid;
            int row = idx >> 3, c4 = idx & 7;
            float4 v = *reinterpret_cast<const float4*>(
                X + (size_t)(m0 + row) * 256 + k0 + c4 * 4);
            __bf16* p = &As[row * 40 + c4 * 4];
            p[0] = (__bf16)v.x; p[1] = (__bf16)v.y;
            p[2] = (__bf16)v.z; p[3] = (__bf16)v.w;
        }
        // stage B tile transposed: W[k0..+32][n0..+128] -> Bs[col][k]
#pragma unroll
        for (int rep = 0; rep < 4; ++rep) {
            int idx = rep * 256 + tid;
            int kk = idx >> 5, n4 = idx & 31;
            float4 v = *reinterpret_cast<const float4*>(
                W + (size_t)(k0 + kk) * 1536 + n0 + n4 * 4);
            Bs[(n4 * 4 + 0) * 40 + kk] = (__bf16)v.x;
            Bs[(n4 * 4 + 1) * 40 + kk] = (__bf16)v.y;
            Bs[(n4 * 4 + 2) * 40 + kk] = (__bf16)v.z;
            Bs[(n4 * 4 + 3) * 40 + kk] = (__bf16)v.w;
        }
        __syncthreads();

        bfx8 af[4], bfr[4];
#pragma unroll
        for (int m = 0; m < 4; ++m)
            af[m] = *reinterpret_cast<const bfx8*>(
                &As[(wr * 64 + m * 16 + l15) * 40 + l4 * 8]);
#pragma unroll
        for (int n = 0; n < 4; ++n)
            bfr[n] = *reinterpret_cast<const bfx8*>(
                &Bs[(wc * 64 + n * 16 + l15) * 40 + l4 * 8]);
#pragma unroll
        for (int m = 0; m < 4; ++m)
#pragma unroll
            for (int n = 0; n < 4; ++n)
                acc[m][n] = mfma16(af[m], bfr[n], acc[m][n]);
    }

    // epilogue: route to Q (scaled) / K / V^T
#pragma unroll
    for (int m = 0; m < 4; ++m)
#pragma unroll
        for (int n = 0; n < 4; ++n)
#pragma unroll
            for (int r = 0; r < 4; ++r) {
                int row = m0 + wr * 64 + m * 16 + l4 * 4 + r;
                int f   = n0 + wc * 64 + n * 16 + l15;
                float v = acc[m][n][r];
                if (f < 512) {
                    Q[(size_t)(f >> 6) * (NTOK * DHEAD) + (size_t)row * DHEAD + (f & 63)] =
                        (__bf16)(v * 0.125f);   // SCALE = 64^-0.5, exact in bf16
                } else if (f < 1024) {
                    int g = f - 512;
                    Kb[(size_t)(g >> 6) * (NTOK * DHEAD) + (size_t)row * DHEAD + (g & 63)] =
                        (__bf16)v;
                } else {
                    int g = f - 1024;
                    Vt[(size_t)(g >> 6) * (DHEAD * NTOK) + (size_t)(g & 63) * NTOK + row] =
                        (__bf16)v;
                }
            }
}

// ============================================================
// Kernel 2: flash attention. block = (qb, head): 64 q-rows, 4 waves x 16 rows.
// K/V fragments straight from global (L2-resident). Online softmax in fp32.
// P goes C-layout -> A-layout via per-wave XOR-swizzled LDS.
// ============================================================
__global__ __launch_bounds__(256) void attn_fwd(
    const __bf16* __restrict__ Q, const __bf16* __restrict__ Kb,
    const __bf16* __restrict__ Vt, __bf16* __restrict__ O)
{
    const int tid  = threadIdx.x;
    const int lane = tid & 63;
    const int wv   = tid >> 6;
    const int h  = blockIdx.y;
    const int qb = blockIdx.x;
    const int l15 = lane & 15, l4 = lane >> 4;

    const __bf16* Qh = Q  + (size_t)h * NTOK * DHEAD;
    const __bf16* Kh = Kb + (size_t)h * NTOK * DHEAD;
    const __bf16* Vh = Vt + (size_t)h * DHEAD * NTOK;

    __shared__ __bf16 Plds[4][16 * 64];   // per-wave 2 KB P buffer (swizzled)
    char* Pw = reinterpret_cast<char*>(&Plds[wv][0]);

    // Q fragments: rows qb*64 + wv*16 + l15, two 32-wide k slices
    const int qrow = qb * 64 + wv * 16 + l15;
    bfx8 qf0 = *reinterpret_cast<const bfx8*>(Qh + (size_t)qrow * DHEAD + l4 * 8);
    bfx8 qf1 = *reinterpret_cast<const bfx8*>(Qh + (size_t)qrow * DHEAD + 32 + l4 * 8);

    f32x4 zero = {0.f, 0.f, 0.f, 0.f};
    f32x4 o[4];
    float mrow[4], lrow[4];
#pragma unroll
    for (int t = 0; t < 4; ++t) o[t] = zero;
#pragma unroll
    for (int r = 0; r < 4; ++r) { mrow[r] = -__builtin_inff(); lrow[r] = 0.f; }

    const float L2E = 1.44269504088896f;

    for (int j0 = 0; j0 < NTOK; j0 += 64) {
        // ---- S = Q K^T for 4 tiles of 16 keys ----
        f32x4 s[4];
#pragma unroll
        for (int t = 0; t < 4; ++t) {
            const __bf16* kp = Kh + (size_t)(j0 + t * 16 + l15) * DHEAD + l4 * 8;
            bfx8 kf0 = *reinterpret_cast<const bfx8*>(kp);
            bfx8 kf1 = *reinterpret_cast<const bfx8*>(kp + 32);
            f32x4 c = zero;
            c = mfma16(qf0, kf0, c);
            c = mfma16(qf1, kf1, c);
            s[t] = c;
        }
        // ---- online softmax (rows (l4*4+r), cols across l15 group) ----
        float tmax[4];
#pragma unroll
        for (int r = 0; r < 4; ++r) {
            float v = fmaxf(fmaxf(s[0][r], s[1][r]), fmaxf(s[2][r], s[3][r]));
#pragma unroll
            for (int msk = 1; msk < 16; msk <<= 1)
                v = fmaxf(v, __shfl_xor(v, msk, 64));
            tmax[r] = v;
        }
        float corr[4], psum[4];
#pragma unroll
        for (int r = 0; r < 4; ++r) {
            float mnew = fmaxf(mrow[r], tmax[r]);
            corr[r] = exp2f((mrow[r] - mnew) * L2E);
            mrow[r] = mnew;
            psum[r] = 0.f;
        }
#pragma unroll
        for (int t = 0; t < 4; ++t)
#pragma unroll
            for (int r = 0; r < 4; ++r) {
                float p = exp2f((s[t][r] - mrow[r]) * L2E);
                psum[r] += p;
                int i = l4 * 4 + r;          // P row (query)
                int j = t * 16 + l15;        // P col (key)
                int byte = (i * 128 + j * 2) ^ ((i & 7) << 4);
                *reinterpret_cast<__bf16*>(Pw + byte) = (__bf16)p;
            }
#pragma unroll
        for (int r = 0; r < 4; ++r) {
#pragma unroll
            for (int msk = 1; msk < 16; msk <<= 1)
                psum[r] += __shfl_xor(psum[r], msk, 64);
            lrow[r] = lrow[r] * corr[r] + psum[r];
        }
#pragma unroll
        for (int t = 0; t < 4; ++t)
#pragma unroll
            for (int r = 0; r < 4; ++r) o[t][r] *= corr[r];

        __syncthreads();   // P writes -> visible for A-layout reads

        bfx8 pf[2];
#pragma unroll
        for (int sI = 0; sI < 2; ++sI) {
            int i = l15;                       // P row for A-operand
            int col = sI * 32 + l4 * 8;        // k (key) offset
            int byte = (i * 128 + col * 2) ^ ((i & 7) << 4);
            pf[sI] = *reinterpret_cast<const bfx8*>(Pw + byte);
        }
        // ---- O += P V : 4 d-tiles x 2 j-slices ----
#pragma unroll
        for (int t = 0; t < 4; ++t) {
            const __bf16* vp = Vh + (size_t)(t * 16 + l15) * NTOK + j0 + l4 * 8;
            bfx8 vf0 = *reinterpret_cast<const bfx8*>(vp);
            bfx8 vf1 = *reinterpret_cast<const bfx8*>(vp + 32);
            o[t] = mfma16(pf[0], vf0, o[t]);
            o[t] = mfma16(pf[1], vf1, o[t]);
        }
        __syncthreads();   // P reads done before next tile overwrites
    }

    // ---- finalize: divide by row sum, store [n][h*64+d] bf16 ----
#pragma unroll
    for (int t = 0; t < 4; ++t)
#pragma unroll
        for (int r = 0; r < 4; ++r) {
            int row = qb * 64 + wv * 16 + l4 * 4 + r;
            int col = h * DHEAD + t * 16 + l15;
            O[(size_t)row * 512 + col] = (__bf16)(o[t][r] / lrow[r]);
        }
}

// ============================================================
// Kernel 3: output projection. O[4096,512] bf16 @ Wout[512,256] fp32 + bias
// tile BM=64 BN=64 BK=32, 4 waves (2x2), wave tile 32x32
// ============================================================
__global__ __launch_bounds__(256) void gemm_out_k(
    const __bf16* __restrict__ O, const float* __restrict__ W,
    const float* __restrict__ bias, float* __restrict__ out)
{
    __shared__ __bf16 As[64 * 40];
    __shared__ __bf16 Bs[64 * 40];
    const int tid  = threadIdx.x;
    const int lane = tid & 63;
    const int wv   = tid >> 6;
    const int wr   = wv >> 1, wc = wv & 1;
    const int m0 = blockIdx.y * 64;
    const int n0 = blockIdx.x * 64;
    const int l15 = lane & 15, l4 = lane >> 4;

    f32x4 zero = {0.f, 0.f, 0.f, 0.f};
    f32x4 acc[2][2];
#pragma unroll
    for (int i = 0; i < 2; ++i)
#pragma unroll
        for (int j = 0; j < 2; ++j) acc[i][j] = zero;

    for (int k0 = 0; k0 < 512; k0 += 32) {
        __syncthreads();
        {   // stage A (already bf16): one 16B vector per thread
            int row = tid >> 2, c8 = tid & 3;
            *reinterpret_cast<bfx8*>(&As[row * 40 + c8 * 8]) =
                *reinterpret_cast<const bfx8*>(O + (size_t)(m0 + row) * 512 + k0 + c8 * 8);
        }
#pragma unroll
        for (int rep = 0; rep < 2; ++rep) {   // stage B transposed fp32->bf16
            int idx = rep * 256 + tid;
            int kk = idx >> 4, n4 = idx & 15;
            float4 v = *reinterpret_cast<const float4*>(
                W + (size_t)(k0 + kk) * 256 + n0 + n4 * 4);
            Bs[(n4 * 4 + 0) * 40 + kk] = (__bf16)v.x;
            Bs[(n4 * 4 + 1) * 40 + kk] = (__bf16)v.y;
            Bs[(n4 * 4 + 2) * 40 + kk] = (__bf16)v.z;
            Bs[(n4 * 4 + 3) * 40 + kk] = (__bf16)v.w;
        }
        __syncthreads();

        bfx8 af[2], bfr[2];
#pragma unroll
        for (int m = 0; m < 2; ++m)
            af[m] = *reinterpret_cast<const bfx8*>(
                &As[(wr * 32 + m * 16 + l15) * 40 + l4 * 8]);
#pragma unroll
        for (int n = 0; n < 2; ++n)
            bfr[n] = *reinterpret_cast<const bfx8*>(
                &Bs[(wc * 32 + n * 16 + l15) * 40 + l4 * 8]);
#pragma unroll
        for (int m = 0; m < 2; ++m)
#pragma unroll
            for (int n = 0; n < 2; ++n)
                acc[m][n] = mfma16(af[m], bfr[n], acc[m][n]);
    }

#pragma unroll
    for (int m = 0; m < 2; ++m)
#pragma unroll
        for (int n = 0; n < 2; ++n)
#pragma unroll
            for (int r = 0; r < 4; ++r) {
                int row = m0 + wr * 32 + m * 16 + l4 * 4 + r;
                int col = n0 + wc * 32 + n * 16 + l15;
                out[(size_t)row * 256 + col] = acc[m][n][r] + bias[col];
            }
}

// ============================================================
extern "C" void kernel_launch(void* const* d_in, const int* in_sizes, int n_in,
                              void* d_out, int out_size, void* d_ws, size_t ws_size,
                              hipStream_t stream) {
    const float* x     = (const float*)d_in[0];
    const float* w_qkv = (const float*)d_in[1];
    const float* w_out = (const float*)d_in[2];
    const float* b_out = (const float*)d_in[3];
    float* out = (float*)d_out;

    // workspace: Q,K (bf16 [8][4096][64]), Vt (bf16 [8][64][4096]), O (bf16 [4096][512])
    __bf16* Q  = (__bf16*)d_ws;
    __bf16* K  = Q  + (size_t)NHEAD * NTOK * DHEAD;
    __bf16* Vt = K  + (size_t)NHEAD * NTOK * DHEAD;
    __bf16* O  = Vt + (size_t)NHEAD * NTOK * DHEAD;

    gemm_qkv  <<<dim3(12, 32), 256, 0, stream>>>(x, w_qkv, Q, K, Vt);
    attn_fwd  <<<dim3(NTOK / 64, NHEAD), 256, 0, stream>>>(Q, K, Vt, O);
    gemm_out_k<<<dim3(256 / 64, NTOK / 64), 256, 0, stream>>>(O, w_out, b_out, out);
}

// Round 2
// 289.980 us; speedup vs baseline: 1.1662x; 1.1662x over previous
//
#include <hip/hip_runtime.h>
#include <hip/hip_bf16.h>

// ---------- types ----------
typedef float f32x4 __attribute__((ext_vector_type(4)));
typedef __bf16 bfx8 __attribute__((ext_vector_type(8)));

#define NTOK 4096
#define NHEAD 8
#define DHEAD 64
#define NSPLIT 4
#define KCHUNK (NTOK / NSPLIT)

__device__ inline f32x4 mfma16(bfx8 a, bfx8 b, f32x4 c) {
    return __builtin_amdgcn_mfma_f32_16x16x32_bf16(a, b, c, 0, 0, 0);
}

// ============================================================
// Kernel 1: QKV projection. X[4096,256] fp32 @ W[256,1536] fp32
//  -> Q[h][n][64] bf16 (×0.125), K[h][n][64] bf16, Vt[h][64][n] bf16
// ============================================================
__global__ __launch_bounds__(256) void gemm_qkv(
    const float* __restrict__ X, const float* __restrict__ W,
    __bf16* __restrict__ Q, __bf16* __restrict__ Kb, __bf16* __restrict__ Vt)
{
    __shared__ __bf16 As[128 * 40];
    __shared__ __bf16 Bs[128 * 40];
    const int tid  = threadIdx.x;
    const int lane = tid & 63;
    const int wv   = tid >> 6;
    const int wr   = wv >> 1, wc = wv & 1;
    const int m0 = blockIdx.y * 128;
    const int n0 = blockIdx.x * 128;
    const int l15 = lane & 15, l4 = lane >> 4;

    f32x4 zero = {0.f, 0.f, 0.f, 0.f};
    f32x4 acc[4][4];
#pragma unroll
    for (int i = 0; i < 4; ++i)
#pragma unroll
        for (int j = 0; j < 4; ++j) acc[i][j] = zero;

    for (int k0 = 0; k0 < 256; k0 += 32) {
        __syncthreads();
#pragma unroll
        for (int rep = 0; rep < 4; ++rep) {
            int idx = rep * 256 + tid;
            int row = idx >> 3, c4 = idx & 7;
            float4 v = *reinterpret_cast<const float4*>(
                X + (size_t)(m0 + row) * 256 + k0 + c4 * 4);
            __bf16* p = &As[row * 40 + c4 * 4];
            p[0] = (__bf16)v.x; p[1] = (__bf16)v.y;
            p[2] = (__bf16)v.z; p[3] = (__bf16)v.w;
        }
#pragma unroll
        for (int rep = 0; rep < 4; ++rep) {
            int idx = rep * 256 + tid;
            int kk = idx >> 5, n4 = idx & 31;
            float4 v = *reinterpret_cast<const float4*>(
                W + (size_t)(k0 + kk) * 1536 + n0 + n4 * 4);
            Bs[(n4 * 4 + 0) * 40 + kk] = (__bf16)v.x;
            Bs[(n4 * 4 + 1) * 40 + kk] = (__bf16)v.y;
            Bs[(n4 * 4 + 2) * 40 + kk] = (__bf16)v.z;
            Bs[(n4 * 4 + 3) * 40 + kk] = (__bf16)v.w;
        }
        __syncthreads();

        bfx8 af[4], bfr[4];
#pragma unroll
        for (int m = 0; m < 4; ++m)
            af[m] = *reinterpret_cast<const bfx8*>(
                &As[(wr * 64 + m * 16 + l15) * 40 + l4 * 8]);
#pragma unroll
        for (int n = 0; n < 4; ++n)
            bfr[n] = *reinterpret_cast<const bfx8*>(
                &Bs[(wc * 64 + n * 16 + l15) * 40 + l4 * 8]);
#pragma unroll
        for (int m = 0; m < 4; ++m)
#pragma unroll
            for (int n = 0; n < 4; ++n)
                acc[m][n] = mfma16(af[m], bfr[n], acc[m][n]);
    }

#pragma unroll
    for (int m = 0; m < 4; ++m)
#pragma unroll
        for (int n = 0; n < 4; ++n)
#pragma unroll
            for (int r = 0; r < 4; ++r) {
                int row = m0 + wr * 64 + m * 16 + l4 * 4 + r;
                int f   = n0 + wc * 64 + n * 16 + l15;
                float v = acc[m][n][r];
                if (f < 512) {
                    Q[(size_t)(f >> 6) * (NTOK * DHEAD) + (size_t)row * DHEAD + (f & 63)] =
                        (__bf16)(v * 0.125f);
                } else if (f < 1024) {
                    int g = f - 512;
                    Kb[(size_t)(g >> 6) * (NTOK * DHEAD) + (size_t)row * DHEAD + (g & 63)] =
                        (__bf16)v;
                } else {
                    int g = f - 1024;
                    Vt[(size_t)(g >> 6) * (DHEAD * NTOK) + (size_t)(g & 63) * NTOK + row] =
                        (__bf16)v;
                }
            }
}

// ============================================================
// Kernel 2: flash attention, KV-split x4 for occupancy.
// block = (qb, head, split): 64 q-rows, 4 waves x 16 rows, 1024 keys.
// No block barriers: P transpose buffer is per-wave (in-order DS ops).
// Writes UNNORMALIZED partial O (fp32) + per-row (m, l).
// ============================================================
__global__ __launch_bounds__(256) void attn_fwd(
    const __bf16* __restrict__ Q, const __bf16* __restrict__ Kb,
    const __bf16* __restrict__ Vt,
    float* __restrict__ Opart, float2* __restrict__ Ml)
{
    const int tid  = threadIdx.x;
    const int lane = tid & 63;
    const int wv   = tid >> 6;
    const int h  = blockIdx.y;
    const int qb = blockIdx.x;
    const int sp = blockIdx.z;
    const int l15 = lane & 15, l4 = lane >> 4;

    const __bf16* Qh = Q  + (size_t)h * NTOK * DHEAD;
    const __bf16* Kh = Kb + (size_t)h * NTOK * DHEAD;
    const __bf16* Vh = Vt + (size_t)h * DHEAD * NTOK;

    __shared__ __bf16 Plds[4][16 * 64];
    char* Pw = reinterpret_cast<char*>(&Plds[wv][0]);

    const int qrow = qb * 64 + wv * 16 + l15;
    bfx8 qf0 = *reinterpret_cast<const bfx8*>(Qh + (size_t)qrow * DHEAD + l4 * 8);
    bfx8 qf1 = *reinterpret_cast<const bfx8*>(Qh + (size_t)qrow * DHEAD + 32 + l4 * 8);

    f32x4 zero = {0.f, 0.f, 0.f, 0.f};
    f32x4 o[4];
    float mrow[4], lrow[4];
#pragma unroll
    for (int t = 0; t < 4; ++t) o[t] = zero;
#pragma unroll
    for (int r = 0; r < 4; ++r) { mrow[r] = -__builtin_inff(); lrow[r] = 0.f; }

    const float L2E = 1.44269504088896f;
    const int jbeg = sp * KCHUNK, jend = jbeg + KCHUNK;

    for (int j0 = jbeg; j0 < jend; j0 += 64) {
        // ---- S = Q K^T ----
        f32x4 s[4];
#pragma unroll
        for (int t = 0; t < 4; ++t) {
            const __bf16* kp = Kh + (size_t)(j0 + t * 16 + l15) * DHEAD + l4 * 8;
            bfx8 kf0 = *reinterpret_cast<const bfx8*>(kp);
            bfx8 kf1 = *reinterpret_cast<const bfx8*>(kp + 32);
            f32x4 c = zero;
            c = mfma16(qf0, kf0, c);
            c = mfma16(qf1, kf1, c);
            s[t] = c;
        }
        // ---- tile max per row ----
        float tmax[4];
#pragma unroll
        for (int r = 0; r < 4; ++r) {
            float v = fmaxf(fmaxf(s[0][r], s[1][r]), fmaxf(s[2][r], s[3][r]));
#pragma unroll
            for (int msk = 1; msk < 16; msk <<= 1)
                v = fmaxf(v, __shfl_xor(v, msk, 64));
            tmax[r] = v;
        }
        // ---- defer-rescale (T13): only rescale if max grew by > 8 ----
        bool grow = (tmax[0] > mrow[0] + 8.f) | (tmax[1] > mrow[1] + 8.f) |
                    (tmax[2] > mrow[2] + 8.f) | (tmax[3] > mrow[3] + 8.f);
        float corr[4];
        if (__ballot(grow)) {
#pragma unroll
            for (int r = 0; r < 4; ++r) {
                float mnew = fmaxf(mrow[r], tmax[r]);
                corr[r] = exp2f((mrow[r] - mnew) * L2E);
                mrow[r] = mnew;
            }
#pragma unroll
            for (int t = 0; t < 4; ++t)
#pragma unroll
                for (int r = 0; r < 4; ++r) o[t][r] *= corr[r];
#pragma unroll
            for (int r = 0; r < 4; ++r) lrow[r] *= corr[r];
        }
        // ---- P = exp(S - m), write transposed to per-wave LDS ----
        float psum[4];
#pragma unroll
        for (int r = 0; r < 4; ++r) psum[r] = 0.f;
#pragma unroll
        for (int t = 0; t < 4; ++t)
#pragma unroll
            for (int r = 0; r < 4; ++r) {
                float p = exp2f((s[t][r] - mrow[r]) * L2E);
                psum[r] += p;
                int i = l4 * 4 + r;
                int j = t * 16 + l15;
                int byte = (i * 128 + j * 2) ^ ((i & 7) << 4);
                *reinterpret_cast<__bf16*>(Pw + byte) = (__bf16)p;
            }
#pragma unroll
        for (int r = 0; r < 4; ++r) {
#pragma unroll
            for (int msk = 1; msk < 16; msk <<= 1)
                psum[r] += __shfl_xor(psum[r], msk, 64);
            lrow[r] += psum[r];
        }

        __builtin_amdgcn_wave_barrier();   // order P writes before reads (same wave)

        bfx8 pf[2];
#pragma unroll
        for (int sI = 0; sI < 2; ++sI) {
            int i = l15;
            int col = sI * 32 + l4 * 8;
            int byte = (i * 128 + col * 2) ^ ((i & 7) << 4);
            pf[sI] = *reinterpret_cast<const bfx8*>(Pw + byte);
        }
        // ---- O += P V ----
#pragma unroll
        for (int t = 0; t < 4; ++t) {
            const __bf16* vp = Vh + (size_t)(t * 16 + l15) * NTOK + j0 + l4 * 8;
            bfx8 vf0 = *reinterpret_cast<const bfx8*>(vp);
            bfx8 vf1 = *reinterpret_cast<const bfx8*>(vp + 32);
            o[t] = mfma16(pf[0], vf0, o[t]);
            o[t] = mfma16(pf[1], vf1, o[t]);
        }
        __builtin_amdgcn_wave_barrier();   // reads done before next overwrite
    }

    // ---- store unnormalized partial O (fp32) + (m,l) per row ----
#pragma unroll
    for (int t = 0; t < 4; ++t)
#pragma unroll
        for (int r = 0; r < 4; ++r) {
            int row = qb * 64 + wv * 16 + l4 * 4 + r;
            int col = h * DHEAD + t * 16 + l15;
            Opart[((size_t)sp * NTOK + row) * 512 + col] = o[t][r];
        }
    if (l15 == 0) {
#pragma unroll
        for (int r = 0; r < 4; ++r) {
            int row = qb * 64 + wv * 16 + l4 * 4 + r;
            Ml[((size_t)sp * NHEAD + h) * NTOK + row] = make_float2(mrow[r], lrow[r]);
        }
    }
}

// ============================================================
// Kernel 2b: combine the NSPLIT partials -> O bf16 [4096][512]
// one thread per (row, 4 cols)
// ============================================================
__global__ __launch_bounds__(256) void attn_combine(
    const float* __restrict__ Opart, const float2* __restrict__ Ml,
    __bf16* __restrict__ O)
{
    const float L2E = 1.44269504088896f;
    int idx = blockIdx.x * 256 + threadIdx.x;      // 4096 * 128
    int row = idx >> 7;
    int c4  = (idx & 127) * 4;
    int h   = c4 >> 6;

    float2 ml[NSPLIT];
    float M = -__builtin_inff();
#pragma unroll
    for (int s = 0; s < NSPLIT; ++s) {
        ml[s] = Ml[((size_t)s * NHEAD + h) * NTOK + row];
        M = fmaxf(M, ml[s].x);
    }
    float denom = 0.f;
    float4 acc = make_float4(0.f, 0.f, 0.f, 0.f);
#pragma unroll
    for (int s = 0; s < NSPLIT; ++s) {
        float w = exp2f((ml[s].x - M) * L2E);
        denom += w * ml[s].y;
        float4 ov = *reinterpret_cast<const float4*>(
            Opart + ((size_t)s * NTOK + row) * 512 + c4);
        acc.x += w * ov.x; acc.y += w * ov.y;
        acc.z += w * ov.z; acc.w += w * ov.w;
    }
    float inv = 1.f / denom;
    __bf16* op = O + (size_t)row * 512 + c4;
    op[0] = (__bf16)(acc.x * inv); op[1] = (__bf16)(acc.y * inv);
    op[2] = (__bf16)(acc.z * inv); op[3] = (__bf16)(acc.w * inv);
}

// ============================================================
// Kernel 3: output projection. O[4096,512] bf16 @ Wout[512,256] fp32 + bias
// ============================================================
__global__ __launch_bounds__(256) void gemm_out_k(
    const __bf16* __restrict__ O, const float* __restrict__ W,
    const float* __restrict__ bias, float* __restrict__ out)
{
    __shared__ __bf16 As[64 * 40];
    __shared__ __bf16 Bs[64 * 40];
    const int tid  = threadIdx.x;
    const int lane = tid & 63;
    const int wv   = tid >> 6;
    const int wr   = wv >> 1, wc = wv & 1;
    const int m0 = blockIdx.y * 64;
    const int n0 = blockIdx.x * 64;
    const int l15 = lane & 15, l4 = lane >> 4;

    f32x4 zero = {0.f, 0.f, 0.f, 0.f};
    f32x4 acc[2][2];
#pragma unroll
    for (int i = 0; i < 2; ++i)
#pragma unroll
        for (int j = 0; j < 2; ++j) acc[i][j] = zero;

    for (int k0 = 0; k0 < 512; k0 += 32) {
        __syncthreads();
        {
            int row = tid >> 2, c8 = tid & 3;
            *reinterpret_cast<bfx8*>(&As[row * 40 + c8 * 8]) =
                *reinterpret_cast<const bfx8*>(O + (size_t)(m0 + row) * 512 + k0 + c8 * 8);
        }
#pragma unroll
        for (int rep = 0; rep < 2; ++rep) {
            int idx = rep * 256 + tid;
            int kk = idx >> 4, n4 = idx & 15;
            float4 v = *reinterpret_cast<const float4*>(
                W + (size_t)(k0 + kk) * 256 + n0 + n4 * 4);
            Bs[(n4 * 4 + 0) * 40 + kk] = (__bf16)v.x;
            Bs[(n4 * 4 + 1) * 40 + kk] = (__bf16)v.y;
            Bs[(n4 * 4 + 2) * 40 + kk] = (__bf16)v.z;
            Bs[(n4 * 4 + 3) * 40 + kk] = (__bf16)v.w;
        }
        __syncthreads();

        bfx8 af[2], bfr[2];
#pragma unroll
        for (int m = 0; m < 2; ++m)
            af[m] = *reinterpret_cast<const bfx8*>(
                &As[(wr * 32 + m * 16 + l15) * 40 + l4 * 8]);
#pragma unroll
        for (int n = 0; n < 2; ++n)
            bfr[n] = *reinterpret_cast<const bfx8*>(
                &Bs[(wc * 32 + n * 16 + l15) * 40 + l4 * 8]);
#pragma unroll
        for (int m = 0; m < 2; ++m)
#pragma unroll
            for (int n = 0; n < 2; ++n)
                acc[m][n] = mfma16(af[m], bfr[n], acc[m][n]);
    }

#pragma unroll
    for (int m = 0; m < 2; ++m)
#pragma unroll
        for (int n = 0; n < 2; ++n)
#pragma unroll
            for (int r = 0; r < 4; ++r) {
                int row = m0 + wr * 32 + m * 16 + l4 * 4 + r;
                int col = n0 + wc * 32 + n * 16 + l15;
                out[(size_t)row * 256 + col] = acc[m][n][r] + bias[col];
            }
}

// ============================================================
extern "C" void kernel_launch(void* const* d_in, const int* in_sizes, int n_in,
                              void* d_out, int out_size, void* d_ws, size_t ws_size,
                              hipStream_t stream) {
    const float* x     = (const float*)d_in[0];
    const float* w_qkv = (const float*)d_in[1];
    const float* w_out = (const float*)d_in[2];
    const float* b_out = (const float*)d_in[3];
    float* out = (float*)d_out;

    // ws layout:
    //  Q,K,Vt  bf16 [8][4096][64] / [8][64][4096]   3 x 4 MB
    //  O       bf16 [4096][512]                     4 MB
    //  Opart   fp32 [NSPLIT][4096][512]             32 MB
    //  Ml      float2 [NSPLIT][8][4096]             1 MB
    __bf16* Q  = (__bf16*)d_ws;
    __bf16* K  = Q  + (size_t)NHEAD * NTOK * DHEAD;
    __bf16* Vt = K  + (size_t)NHEAD * NTOK * DHEAD;
    __bf16* O  = Vt + (size_t)NHEAD * NTOK * DHEAD;
    float*  Opart = (float*)(O + (size_t)NTOK * 512);
    float2* Ml    = (float2*)(Opart + (size_t)NSPLIT * NTOK * 512);

    gemm_qkv    <<<dim3(12, 32), 256, 0, stream>>>(x, w_qkv, Q, K, Vt);
    attn_fwd    <<<dim3(NTOK / 64, NHEAD, NSPLIT), 256, 0, stream>>>(Q, K, Vt, Opart, Ml);
    attn_combine<<<dim3(NTOK * 128 / 256), 256, 0, stream>>>(Opart, Ml, O);
    gemm_out_k  <<<dim3(256 / 64, NTOK / 64), 256, 0, stream>>>(O, w_out, b_out, out);
}

// Round 3
// 169.057 us; speedup vs baseline: 2.0003x; 1.7153x over previous
//
#include <hip/hip_runtime.h>
#include <hip/hip_bf16.h>

// ---------- types ----------
typedef float f32x4 __attribute__((ext_vector_type(4)));
typedef __bf16 bfx8 __attribute__((ext_vector_type(8)));

#define NTOK 4096
#define NHEAD 8
#define DHEAD 64
#define NSPLIT 2
#define KCHUNK (NTOK / NSPLIT)

__device__ inline f32x4 mfma16(bfx8 a, bfx8 b, f32x4 c) {
    return __builtin_amdgcn_mfma_f32_16x16x32_bf16(a, b, c, 0, 0, 0);
}

__device__ __forceinline__ void gld_lds16(const __bf16* g, __bf16* lds) {
    __builtin_amdgcn_global_load_lds(
        (const __attribute__((address_space(1))) void*)g,
        (__attribute__((address_space(3))) void*)lds, 16, 0, 0);
}

// ============================================================
// Kernel 1: QKV projection. X[4096,256] fp32 @ W[256,1536] fp32
//  -> Q[h][n][64] bf16 (×0.125), K[h][n][64] bf16, Vt[h][64][n] bf16
// ============================================================
__global__ __launch_bounds__(256) void gemm_qkv(
    const float* __restrict__ X, const float* __restrict__ W,
    __bf16* __restrict__ Q, __bf16* __restrict__ Kb, __bf16* __restrict__ Vt)
{
    __shared__ __bf16 As[128 * 40];
    __shared__ __bf16 Bs[128 * 40];
    const int tid  = threadIdx.x;
    const int lane = tid & 63;
    const int wv   = tid >> 6;
    const int wr   = wv >> 1, wc = wv & 1;
    const int m0 = blockIdx.y * 128;
    const int n0 = blockIdx.x * 128;
    const int l15 = lane & 15, l4 = lane >> 4;

    f32x4 zero = {0.f, 0.f, 0.f, 0.f};
    f32x4 acc[4][4];
#pragma unroll
    for (int i = 0; i < 4; ++i)
#pragma unroll
        for (int j = 0; j < 4; ++j) acc[i][j] = zero;

    for (int k0 = 0; k0 < 256; k0 += 32) {
        __syncthreads();
#pragma unroll
        for (int rep = 0; rep < 4; ++rep) {
            int idx = rep * 256 + tid;
            int row = idx >> 3, c4 = idx & 7;
            float4 v = *reinterpret_cast<const float4*>(
                X + (size_t)(m0 + row) * 256 + k0 + c4 * 4);
            __bf16* p = &As[row * 40 + c4 * 4];
            p[0] = (__bf16)v.x; p[1] = (__bf16)v.y;
            p[2] = (__bf16)v.z; p[3] = (__bf16)v.w;
        }
#pragma unroll
        for (int rep = 0; rep < 4; ++rep) {
            int idx = rep * 256 + tid;
            int kk = idx >> 5, n4 = idx & 31;
            float4 v = *reinterpret_cast<const float4*>(
                W + (size_t)(k0 + kk) * 1536 + n0 + n4 * 4);
            Bs[(n4 * 4 + 0) * 40 + kk] = (__bf16)v.x;
            Bs[(n4 * 4 + 1) * 40 + kk] = (__bf16)v.y;
            Bs[(n4 * 4 + 2) * 40 + kk] = (__bf16)v.z;
            Bs[(n4 * 4 + 3) * 40 + kk] = (__bf16)v.w;
        }
        __syncthreads();

        bfx8 af[4], bfr[4];
#pragma unroll
        for (int m = 0; m < 4; ++m)
            af[m] = *reinterpret_cast<const bfx8*>(
                &As[(wr * 64 + m * 16 + l15) * 40 + l4 * 8]);
#pragma unroll
        for (int n = 0; n < 4; ++n)
            bfr[n] = *reinterpret_cast<const bfx8*>(
                &Bs[(wc * 64 + n * 16 + l15) * 40 + l4 * 8]);
#pragma unroll
        for (int m = 0; m < 4; ++m)
#pragma unroll
            for (int n = 0; n < 4; ++n)
                acc[m][n] = mfma16(af[m], bfr[n], acc[m][n]);
    }

#pragma unroll
    for (int m = 0; m < 4; ++m)
#pragma unroll
        for (int n = 0; n < 4; ++n)
#pragma unroll
            for (int r = 0; r < 4; ++r) {
                int row = m0 + wr * 64 + m * 16 + l4 * 4 + r;
                int f   = n0 + wc * 64 + n * 16 + l15;
                float v = acc[m][n][r];
                if (f < 512) {
                    Q[(size_t)(f >> 6) * (NTOK * DHEAD) + (size_t)row * DHEAD + (f & 63)] =
                        (__bf16)(v * 0.125f);
                } else if (f < 1024) {
                    int g = f - 512;
                    Kb[(size_t)(g >> 6) * (NTOK * DHEAD) + (size_t)row * DHEAD + (g & 63)] =
                        (__bf16)v;
                } else {
                    int g = f - 1024;
                    Vt[(size_t)(g >> 6) * (DHEAD * NTOK) + (size_t)(g & 63) * NTOK + row] =
                        (__bf16)v;
                }
            }
}

// ============================================================
// Kernel 2: flash attention, LDS-staged K/V, double-buffered, KV-split x2.
// flat grid, bid%8 == head  -> each head pinned to one XCD's L2.
// block = 4 waves x 16 q-rows = 64 q-rows, 64 keys/tile.
// K/V tiles staged once per block via global_load_lds (pre-swizzled source,
// XOR-swizzled reads: byte ^= (row&7)<<4  — T2 / rule #21 both-sides).
// ============================================================
__global__ __launch_bounds__(256) void attn_fwd(
    const __bf16* __restrict__ Q, const __bf16* __restrict__ Kb,
    const __bf16* __restrict__ Vt,
    float* __restrict__ Opart, float2* __restrict__ Ml)
{
    const int tid  = threadIdx.x;
    const int lane = tid & 63;
    const int wv   = tid >> 6;
    const int bid = blockIdx.x;
    const int h  = bid & 7;
    const int t2 = bid >> 3;
    const int sp = t2 & 1;
    const int qb = t2 >> 1;
    const int l15 = lane & 15, l4 = lane >> 4;

    const __bf16* Qh = Q  + (size_t)h * NTOK * DHEAD;
    const __bf16* Kh = Kb + (size_t)h * NTOK * DHEAD;
    const __bf16* Vh = Vt + (size_t)h * DHEAD * NTOK;

    __shared__ __bf16 Ks[2][64 * 64];     // 8 KB x2
    __shared__ __bf16 Vs[2][64 * 64];     // 8 KB x2
    __shared__ __bf16 Plds[4][16 * 64];   // per-wave P transpose, 2 KB each
    char* Pw = reinterpret_cast<char*>(&Plds[wv][0]);

    // staging address precompute (pre-swizzled global source)
    const int srow  = tid >> 3;                       // 0..31 (row within 32-row half)
    const int scol8 = (tid & 7) ^ (srow & 7);         // swizzled 8-elem column group

    const int qrow = qb * 64 + wv * 16 + l15;
    bfx8 qf0 = *reinterpret_cast<const bfx8*>(Qh + (size_t)qrow * DHEAD + l4 * 8);
    bfx8 qf1 = *reinterpret_cast<const bfx8*>(Qh + (size_t)qrow * DHEAD + 32 + l4 * 8);

    f32x4 zero = {0.f, 0.f, 0.f, 0.f};
    f32x4 o[4];
    float mrow[4], lrow[4];
#pragma unroll
    for (int t = 0; t < 4; ++t) o[t] = zero;
#pragma unroll
    for (int r = 0; r < 4; ++r) { mrow[r] = -__builtin_inff(); lrow[r] = 0.f; }

    const float L2E = 1.44269504088896f;
    const int jbeg = sp * KCHUNK, jend = jbeg + KCHUNK;

    auto stage = [&](int buf, int j0) {
#pragma unroll
        for (int i = 0; i < 2; ++i) {
            // wave-uniform LDS base; HW adds lane*16B
            gld_lds16(Kh + (size_t)(j0 + i * 32 + srow) * DHEAD + scol8 * 8,
                      &Ks[buf][(i * 32 + wv * 8) * 64]);
            gld_lds16(Vh + (size_t)(i * 32 + srow) * NTOK + j0 + scol8 * 8,
                      &Vs[buf][(i * 32 + wv * 8) * 64]);
        }
    };

    stage(0, jbeg);
    __syncthreads();

    int buf = 0;
    for (int j0 = jbeg; j0 < jend; j0 += 64) {
        if (j0 + 64 < jend) stage(buf ^ 1, j0 + 64);

        const char* Kc = reinterpret_cast<const char*>(&Ks[buf][0]);
        const char* Vc = reinterpret_cast<const char*>(&Vs[buf][0]);

        // ---- S = Q K^T (K from swizzled LDS) ----
        f32x4 s[4];
#pragma unroll
        for (int t = 0; t < 4; ++t) {
            int row = t * 16 + l15;
            int sw  = (l15 & 7) << 4;
            bfx8 kf0 = *reinterpret_cast<const bfx8*>(Kc + row * 128 + ((l4 * 16) ^ sw));
            bfx8 kf1 = *reinterpret_cast<const bfx8*>(Kc + row * 128 + ((64 + l4 * 16) ^ sw));
            f32x4 c = zero;
            c = mfma16(qf0, kf0, c);
            c = mfma16(qf1, kf1, c);
            s[t] = c;
        }
        // ---- tile max per row ----
        float tmax[4];
#pragma unroll
        for (int r = 0; r < 4; ++r) {
            float v = fmaxf(fmaxf(s[0][r], s[1][r]), fmaxf(s[2][r], s[3][r]));
#pragma unroll
            for (int msk = 1; msk < 16; msk <<= 1)
                v = fmaxf(v, __shfl_xor(v, msk, 64));
            tmax[r] = v;
        }
        // ---- defer-rescale (T13, THR=8) ----
        bool grow = (tmax[0] > mrow[0] + 8.f) | (tmax[1] > mrow[1] + 8.f) |
                    (tmax[2] > mrow[2] + 8.f) | (tmax[3] > mrow[3] + 8.f);
        float corr[4];
        if (__ballot(grow)) {
#pragma unroll
            for (int r = 0; r < 4; ++r) {
                float mnew = fmaxf(mrow[r], tmax[r]);
                corr[r] = exp2f((mrow[r] - mnew) * L2E);
                mrow[r] = mnew;
            }
#pragma unroll
            for (int t = 0; t < 4; ++t)
#pragma unroll
                for (int r = 0; r < 4; ++r) o[t][r] *= corr[r];
#pragma unroll
            for (int r = 0; r < 4; ++r) lrow[r] *= corr[r];
        }
        // ---- P = exp(S - m), transpose via per-wave swizzled LDS ----
        float psum[4];
#pragma unroll
        for (int r = 0; r < 4; ++r) psum[r] = 0.f;
#pragma unroll
        for (int t = 0; t < 4; ++t)
#pragma unroll
            for (int r = 0; r < 4; ++r) {
                float p = exp2f((s[t][r] - mrow[r]) * L2E);
                psum[r] += p;
                int i = l4 * 4 + r;
                int j = t * 16 + l15;
                int byte = (i * 128 + j * 2) ^ ((i & 7) << 4);
                *reinterpret_cast<__bf16*>(Pw + byte) = (__bf16)p;
            }
#pragma unroll
        for (int r = 0; r < 4; ++r) {
#pragma unroll
            for (int msk = 1; msk < 16; msk <<= 1)
                psum[r] += __shfl_xor(psum[r], msk, 64);
            lrow[r] += psum[r];
        }

        __builtin_amdgcn_wave_barrier();   // same-wave P write->read ordering

        bfx8 pf[2];
#pragma unroll
        for (int sI = 0; sI < 2; ++sI) {
            int i = l15;
            int col = sI * 32 + l4 * 8;
            int byte = (i * 128 + col * 2) ^ ((i & 7) << 4);
            pf[sI] = *reinterpret_cast<const bfx8*>(Pw + byte);
        }
        // ---- O += P V (V from swizzled LDS) ----
#pragma unroll
        for (int t = 0; t < 4; ++t) {
            int row = t * 16 + l15;
            int sw  = (l15 & 7) << 4;
            bfx8 vf0 = *reinterpret_cast<const bfx8*>(Vc + row * 128 + ((l4 * 16) ^ sw));
            bfx8 vf1 = *reinterpret_cast<const bfx8*>(Vc + row * 128 + ((64 + l4 * 16) ^ sw));
            o[t] = mfma16(pf[0], vf0, o[t]);
            o[t] = mfma16(pf[1], vf1, o[t]);
        }

        __syncthreads();   // staged buf^1 complete; P reads done before next overwrite
        buf ^= 1;
    }

    // ---- store unnormalized partial O (fp32) + (m,l) ----
#pragma unroll
    for (int t = 0; t < 4; ++t)
#pragma unroll
        for (int r = 0; r < 4; ++r) {
            int row = qb * 64 + wv * 16 + l4 * 4 + r;
            int col = h * DHEAD + t * 16 + l15;
            Opart[((size_t)sp * NTOK + row) * 512 + col] = o[t][r];
        }
    if (l15 == 0) {
#pragma unroll
        for (int r = 0; r < 4; ++r) {
            int row = qb * 64 + wv * 16 + l4 * 4 + r;
            Ml[((size_t)sp * NHEAD + h) * NTOK + row] = make_float2(mrow[r], lrow[r]);
        }
    }
}

// ============================================================
// Kernel 2b: combine NSPLIT partials -> O bf16 [4096][512]
// ============================================================
__global__ __launch_bounds__(256) void attn_combine(
    const float* __restrict__ Opart, const float2* __restrict__ Ml,
    __bf16* __restrict__ O)
{
    const float L2E = 1.44269504088896f;
    int idx = blockIdx.x * 256 + threadIdx.x;      // 4096 * 128
    int row = idx >> 7;
    int c4  = (idx & 127) * 4;
    int h   = c4 >> 6;

    float2 ml[NSPLIT];
    float M = -__builtin_inff();
#pragma unroll
    for (int s = 0; s < NSPLIT; ++s) {
        ml[s] = Ml[((size_t)s * NHEAD + h) * NTOK + row];
        M = fmaxf(M, ml[s].x);
    }
    float denom = 0.f;
    float4 acc = make_float4(0.f, 0.f, 0.f, 0.f);
#pragma unroll
    for (int s = 0; s < NSPLIT; ++s) {
        float w = exp2f((ml[s].x - M) * L2E);
        denom += w * ml[s].y;
        float4 ov = *reinterpret_cast<const float4*>(
            Opart + ((size_t)s * NTOK + row) * 512 + c4);
        acc.x += w * ov.x; acc.y += w * ov.y;
        acc.z += w * ov.z; acc.w += w * ov.w;
    }
    float inv = 1.f / denom;
    __bf16* op = O + (size_t)row * 512 + c4;
    op[0] = (__bf16)(acc.x * inv); op[1] = (__bf16)(acc.y * inv);
    op[2] = (__bf16)(acc.z * inv); op[3] = (__bf16)(acc.w * inv);
}

// ============================================================
// Kernel 3: output projection. O[4096,512] bf16 @ Wout[512,256] fp32 + bias
// ============================================================
__global__ __launch_bounds__(256) void gemm_out_k(
    const __bf16* __restrict__ O, const float* __restrict__ W,
    const float* __restrict__ bias, float* __restrict__ out)
{
    __shared__ __bf16 As[64 * 40];
    __shared__ __bf16 Bs[64 * 40];
    const int tid  = threadIdx.x;
    const int lane = tid & 63;
    const int wv   = tid >> 6;
    const int wr   = wv >> 1, wc = wv & 1;
    const int m0 = blockIdx.y * 64;
    const int n0 = blockIdx.x * 64;
    const int l15 = lane & 15, l4 = lane >> 4;

    f32x4 zero = {0.f, 0.f, 0.f, 0.f};
    f32x4 acc[2][2];
#pragma unroll
    for (int i = 0; i < 2; ++i)
#pragma unroll
        for (int j = 0; j < 2; ++j) acc[i][j] = zero;

    for (int k0 = 0; k0 < 512; k0 += 32) {
        __syncthreads();
        {
            int row = tid >> 2, c8 = tid & 3;
            *reinterpret_cast<bfx8*>(&As[row * 40 + c8 * 8]) =
                *reinterpret_cast<const bfx8*>(O + (size_t)(m0 + row) * 512 + k0 + c8 * 8);
        }
#pragma unroll
        for (int rep = 0; rep < 2; ++rep) {
            int idx = rep * 256 + tid;
            int kk = idx >> 4, n4 = idx & 15;
            float4 v = *reinterpret_cast<const float4*>(
                W + (size_t)(k0 + kk) * 256 + n0 + n4 * 4);
            Bs[(n4 * 4 + 0) * 40 + kk] = (__bf16)v.x;
            Bs[(n4 * 4 + 1) * 40 + kk] = (__bf16)v.y;
            Bs[(n4 * 4 + 2) * 40 + kk] = (__bf16)v.z;
            Bs[(n4 * 4 + 3) * 40 + kk] = (__bf16)v.w;
        }
        __syncthreads();

        bfx8 af[2], bfr[2];
#pragma unroll
        for (int m = 0; m < 2; ++m)
            af[m] = *reinterpret_cast<const bfx8*>(
                &As[(wr * 32 + m * 16 + l15) * 40 + l4 * 8]);
#pragma unroll
        for (int n = 0; n < 2; ++n)
            bfr[n] = *reinterpret_cast<const bfx8*>(
                &Bs[(wc * 32 + n * 16 + l15) * 40 + l4 * 8]);
#pragma unroll
        for (int m = 0; m < 2; ++m)
#pragma unroll
            for (int n = 0; n < 2; ++n)
                acc[m][n] = mfma16(af[m], bfr[n], acc[m][n]);
    }

#pragma unroll
    for (int m = 0; m < 2; ++m)
#pragma unroll
        for (int n = 0; n < 2; ++n)
#pragma unroll
            for (int r = 0; r < 4; ++r) {
                int row = m0 + wr * 32 + m * 16 + l4 * 4 + r;
                int col = n0 + wc * 32 + n * 16 + l15;
                out[(size_t)row * 256 + col] = acc[m][n][r] + bias[col];
            }
}

// ============================================================
extern "C" void kernel_launch(void* const* d_in, const int* in_sizes, int n_in,
                              void* d_out, int out_size, void* d_ws, size_t ws_size,
                              hipStream_t stream) {
    const float* x     = (const float*)d_in[0];
    const float* w_qkv = (const float*)d_in[1];
    const float* w_out = (const float*)d_in[2];
    const float* b_out = (const float*)d_in[3];
    float* out = (float*)d_out;

    __bf16* Q  = (__bf16*)d_ws;
    __bf16* K  = Q  + (size_t)NHEAD * NTOK * DHEAD;
    __bf16* Vt = K  + (size_t)NHEAD * NTOK * DHEAD;
    __bf16* O  = Vt + (size_t)NHEAD * NTOK * DHEAD;
    float*  Opart = (float*)(O + (size_t)NTOK * 512);
    float2* Ml    = (float2*)(Opart + (size_t)NSPLIT * NTOK * 512);

    gemm_qkv    <<<dim3(12, 32), 256, 0, stream>>>(x, w_qkv, Q, K, Vt);
    // flat grid: bid%8 == head -> per-head XCD pinning
    attn_fwd    <<<dim3((NTOK / 64) * NSPLIT * NHEAD), 256, 0, stream>>>(Q, K, Vt, Opart, Ml);
    attn_combine<<<dim3(NTOK * 128 / 256), 256, 0, stream>>>(Opart, Ml, O);
    gemm_out_k  <<<dim3(256 / 64, NTOK / 64), 256, 0, stream>>>(O, w_out, b_out, out);
}

// Round 4
// 133.068 us; speedup vs baseline: 2.5413x; 1.2705x over previous
//
#include <hip/hip_runtime.h>
#include <hip/hip_bf16.h>

// ---------- types ----------
typedef float f32x4 __attribute__((ext_vector_type(4)));
typedef __bf16 bfx8 __attribute__((ext_vector_type(8)));

#define NTOK 4096
#define NHEAD 8
#define DHEAD 64
#define NSPLIT 2
#define KCHUNK (NTOK / NSPLIT)

__device__ inline f32x4 mfma16(bfx8 a, bfx8 b, f32x4 c) {
    return __builtin_amdgcn_mfma_f32_16x16x32_bf16(a, b, c, 0, 0, 0);
}

__device__ __forceinline__ void gld_lds16(const __bf16* g, __bf16* lds) {
    __builtin_amdgcn_global_load_lds(
        (const __attribute__((address_space(1))) void*)g,
        (__attribute__((address_space(3))) void*)lds, 16, 0, 0);
}

// ============================================================
// Kernel 1: QKV projection. X[4096,256] fp32 @ W[256,1536] fp32
//  -> Q[h][n][64] bf16 (x 0.125*log2e), K[h][n][64] bf16, Vt[h][64][n] bf16
// Q pre-scaled so attention logits are in log2 units (exp2 direct).
// ============================================================
__global__ __launch_bounds__(256) void gemm_qkv(
    const float* __restrict__ X, const float* __restrict__ W,
    __bf16* __restrict__ Q, __bf16* __restrict__ Kb, __bf16* __restrict__ Vt)
{
    __shared__ __bf16 As[128 * 40];
    __shared__ __bf16 Bs[128 * 40];
    const int tid  = threadIdx.x;
    const int lane = tid & 63;
    const int wv   = tid >> 6;
    const int wr   = wv >> 1, wc = wv & 1;
    const int m0 = blockIdx.y * 128;
    const int n0 = blockIdx.x * 128;
    const int l15 = lane & 15, l4 = lane >> 4;

    f32x4 zero = {0.f, 0.f, 0.f, 0.f};
    f32x4 acc[4][4];
#pragma unroll
    for (int i = 0; i < 4; ++i)
#pragma unroll
        for (int j = 0; j < 4; ++j) acc[i][j] = zero;

    for (int k0 = 0; k0 < 256; k0 += 32) {
        __syncthreads();
#pragma unroll
        for (int rep = 0; rep < 4; ++rep) {
            int idx = rep * 256 + tid;
            int row = idx >> 3, c4 = idx & 7;
            float4 v = *reinterpret_cast<const float4*>(
                X + (size_t)(m0 + row) * 256 + k0 + c4 * 4);
            __bf16* p = &As[row * 40 + c4 * 4];
            p[0] = (__bf16)v.x; p[1] = (__bf16)v.y;
            p[2] = (__bf16)v.z; p[3] = (__bf16)v.w;
        }
#pragma unroll
        for (int rep = 0; rep < 4; ++rep) {
            int idx = rep * 256 + tid;
            int kk = idx >> 5, n4 = idx & 31;
            float4 v = *reinterpret_cast<const float4*>(
                W + (size_t)(k0 + kk) * 1536 + n0 + n4 * 4);
            Bs[(n4 * 4 + 0) * 40 + kk] = (__bf16)v.x;
            Bs[(n4 * 4 + 1) * 40 + kk] = (__bf16)v.y;
            Bs[(n4 * 4 + 2) * 40 + kk] = (__bf16)v.z;
            Bs[(n4 * 4 + 3) * 40 + kk] = (__bf16)v.w;
        }
        __syncthreads();

        bfx8 af[4], bfr[4];
#pragma unroll
        for (int m = 0; m < 4; ++m)
            af[m] = *reinterpret_cast<const bfx8*>(
                &As[(wr * 64 + m * 16 + l15) * 40 + l4 * 8]);
#pragma unroll
        for (int n = 0; n < 4; ++n)
            bfr[n] = *reinterpret_cast<const bfx8*>(
                &Bs[(wc * 64 + n * 16 + l15) * 40 + l4 * 8]);
#pragma unroll
        for (int m = 0; m < 4; ++m)
#pragma unroll
            for (int n = 0; n < 4; ++n)
                acc[m][n] = mfma16(af[m], bfr[n], acc[m][n]);
    }

    const float QSCALE = 0.125f * 1.44269504088896f;   // dim^-0.5 * log2(e)
#pragma unroll
    for (int m = 0; m < 4; ++m)
#pragma unroll
        for (int n = 0; n < 4; ++n)
#pragma unroll
            for (int r = 0; r < 4; ++r) {
                int row = m0 + wr * 64 + m * 16 + l4 * 4 + r;
                int f   = n0 + wc * 64 + n * 16 + l15;
                float v = acc[m][n][r];
                if (f < 512) {
                    Q[(size_t)(f >> 6) * (NTOK * DHEAD) + (size_t)row * DHEAD + (f & 63)] =
                        (__bf16)(v * QSCALE);
                } else if (f < 1024) {
                    int g = f - 512;
                    Kb[(size_t)(g >> 6) * (NTOK * DHEAD) + (size_t)row * DHEAD + (g & 63)] =
                        (__bf16)v;
                } else {
                    int g = f - 1024;
                    Vt[(size_t)(g >> 6) * (DHEAD * NTOK) + (size_t)(g & 63) * NTOK + row] =
                        (__bf16)v;
                }
            }
}

// ============================================================
// Kernel 2: flash attention, swapped QK^T (S' = K x Q^T) so each lane owns
// one q-row's 16 logits -> in-register softmax (15 fmax + 2 shfl).
// LDS-staged double-buffered K/V (XOR-swizzled), KV-split x2, flat grid
// bid%8 == head for XCD L2 pinning. Logits in log2 units (Q pre-scaled).
// ============================================================
__global__ __launch_bounds__(256) void attn_fwd(
    const __bf16* __restrict__ Q, const __bf16* __restrict__ Kb,
    const __bf16* __restrict__ Vt,
    float* __restrict__ Opart, float2* __restrict__ Ml)
{
    const int tid  = threadIdx.x;
    const int lane = tid & 63;
    const int wv   = tid >> 6;
    const int bid = blockIdx.x;
    const int h  = bid & 7;
    const int t2 = bid >> 3;
    const int sp = t2 & 1;
    const int qb = t2 >> 1;
    const int l15 = lane & 15, l4 = lane >> 4;

    const __bf16* Qh = Q  + (size_t)h * NTOK * DHEAD;
    const __bf16* Kh = Kb + (size_t)h * NTOK * DHEAD;
    const __bf16* Vh = Vt + (size_t)h * DHEAD * NTOK;

    __shared__ __bf16 Ks[2][64 * 64];
    __shared__ __bf16 Vs[2][64 * 64];
    __shared__ __bf16 Plds[4][16 * 64];
    char* Pw = reinterpret_cast<char*>(&Plds[wv][0]);

    const int srow  = tid >> 3;
    const int scol8 = (tid & 7) ^ (srow & 7);

    const int qrow = qb * 64 + wv * 16 + l15;
    bfx8 qf0 = *reinterpret_cast<const bfx8*>(Qh + (size_t)qrow * DHEAD + l4 * 8);
    bfx8 qf1 = *reinterpret_cast<const bfx8*>(Qh + (size_t)qrow * DHEAD + 32 + l4 * 8);

    f32x4 zero = {0.f, 0.f, 0.f, 0.f};
    f32x4 o[4];
#pragma unroll
    for (int t = 0; t < 4; ++t) o[t] = zero;
    float m_l = -__builtin_inff();   // running max for q-row l15 (log2 units)
    float l_l = 0.f;                 // running denom for q-row l15

    const int jbeg = sp * KCHUNK, jend = jbeg + KCHUNK;

    auto stage = [&](int buf, int j0) {
#pragma unroll
        for (int i = 0; i < 2; ++i) {
            gld_lds16(Kh + (size_t)(j0 + i * 32 + srow) * DHEAD + scol8 * 8,
                      &Ks[buf][(i * 32 + wv * 8) * 64]);
            gld_lds16(Vh + (size_t)(i * 32 + srow) * NTOK + j0 + scol8 * 8,
                      &Vs[buf][(i * 32 + wv * 8) * 64]);
        }
    };

    stage(0, jbeg);
    __syncthreads();

    int buf = 0;
    for (int j0 = jbeg; j0 < jend; j0 += 64) {
        if (j0 + 64 < jend) stage(buf ^ 1, j0 + 64);

        const char* Kc = reinterpret_cast<const char*>(&Ks[buf][0]);
        const char* Vc = reinterpret_cast<const char*>(&Vs[buf][0]);

        // ---- S' = K Q^T : lane holds S[q=l15][k = t*16 + l4*4 + r] ----
        f32x4 s[4];
#pragma unroll
        for (int t = 0; t < 4; ++t) {
            int row = t * 16 + l15;
            int sw  = (l15 & 7) << 4;
            bfx8 kf0 = *reinterpret_cast<const bfx8*>(Kc + row * 128 + ((l4 * 16) ^ sw));
            bfx8 kf1 = *reinterpret_cast<const bfx8*>(Kc + row * 128 + ((64 + l4 * 16) ^ sw));
            f32x4 c = zero;
            c = mfma16(kf0, qf0, c);
            c = mfma16(kf1, qf1, c);
            s[t] = c;
        }

        // ---- tile max (in-register + 2 shuffles) ----
        float tm = fmaxf(fmaxf(fmaxf(s[0][0], s[0][1]), fmaxf(s[0][2], s[0][3])),
                         fmaxf(fmaxf(s[1][0], s[1][1]), fmaxf(s[1][2], s[1][3])));
        tm = fmaxf(tm,
             fmaxf(fmaxf(fmaxf(s[2][0], s[2][1]), fmaxf(s[2][2], s[2][3])),
                   fmaxf(fmaxf(s[3][0], s[3][1]), fmaxf(s[3][2], s[3][3]))));
        tm = fmaxf(tm, __shfl_xor(tm, 16, 64));
        tm = fmaxf(tm, __shfl_xor(tm, 32, 64));

        // ---- defer-rescale (T13): THR = 8 nats = 11.54 log2 ----
        bool grow = tm > m_l + 11.5416f;
        if (__ballot(grow)) {
            float mnew = fmaxf(m_l, tm);
            float corr = exp2f(m_l - mnew);
            m_l = mnew;
            l_l *= corr;
#pragma unroll
            for (int r = 0; r < 4; ++r) {
                float cr = __shfl(corr, l4 * 4 + r, 64);
#pragma unroll
                for (int t = 0; t < 4; ++t) o[t][r] *= cr;
            }
        }

        // ---- P = exp2(S - m); pack 4 bf16 -> one ds_write_b64 per tile ----
        float psum = 0.f;
#pragma unroll
        for (int t = 0; t < 4; ++t) {
            float p0 = exp2f(s[t][0] - m_l);
            float p1 = exp2f(s[t][1] - m_l);
            float p2 = exp2f(s[t][2] - m_l);
            float p3 = exp2f(s[t][3] - m_l);
            psum += (p0 + p1) + (p2 + p3);
            int k0 = t * 16 + l4 * 4;
            int b0 = (l15 * 128 + k0 * 2) ^ ((l15 & 7) << 4);
            union { __bf16 h[4]; int2 u2; } wq;
            wq.h[0] = (__bf16)p0; wq.h[1] = (__bf16)p1;
            wq.h[2] = (__bf16)p2; wq.h[3] = (__bf16)p3;
            *reinterpret_cast<int2*>(Pw + b0) = wq.u2;
        }
        psum += __shfl_xor(psum, 16, 64);
        psum += __shfl_xor(psum, 32, 64);
        l_l += psum;

        __builtin_amdgcn_wave_barrier();   // same-wave P write->read ordering

        // ---- A-fragments of P: lane q=l15, k = sI*32 + l4*8 .. +8 ----
        bfx8 pf[2];
#pragma unroll
        for (int sI = 0; sI < 2; ++sI) {
            int byte = (l15 * 128 + (sI * 64 + l4 * 16)) ^ ((l15 & 7) << 4);
            pf[sI] = *reinterpret_cast<const bfx8*>(Pw + byte);
        }
        // ---- O += P V (V from swizzled LDS) ----
#pragma unroll
        for (int t = 0; t < 4; ++t) {
            int row = t * 16 + l15;
            int sw  = (l15 & 7) << 4;
            bfx8 vf0 = *reinterpret_cast<const bfx8*>(Vc + row * 128 + ((l4 * 16) ^ sw));
            bfx8 vf1 = *reinterpret_cast<const bfx8*>(Vc + row * 128 + ((64 + l4 * 16) ^ sw));
            o[t] = mfma16(pf[0], vf0, o[t]);
            o[t] = mfma16(pf[1], vf1, o[t]);
        }

        __syncthreads();   // staged buf^1 complete; P reads done before overwrite
        buf ^= 1;
    }

    // ---- store unnormalized partial O (fp32) + per-row (m, l) ----
#pragma unroll
    for (int t = 0; t < 4; ++t)
#pragma unroll
        for (int r = 0; r < 4; ++r) {
            int row = qb * 64 + wv * 16 + l4 * 4 + r;
            int col = h * DHEAD + t * 16 + l15;
            Opart[((size_t)sp * NTOK + row) * 512 + col] = o[t][r];
        }
    if (lane < 16) {
        int row = qb * 64 + wv * 16 + lane;
        Ml[((size_t)sp * NHEAD + h) * NTOK + row] = make_float2(m_l, l_l);
    }
}

// ============================================================
// Kernel 2b: combine NSPLIT partials -> O bf16 [4096][512]
// (m is in log2 units: weights are exp2(m - M) directly)
// ============================================================
__global__ __launch_bounds__(256) void attn_combine(
    const float* __restrict__ Opart, const float2* __restrict__ Ml,
    __bf16* __restrict__ O)
{
    int idx = blockIdx.x * 256 + threadIdx.x;      // 4096 * 128
    int row = idx >> 7;
    int c4  = (idx & 127) * 4;
    int h   = c4 >> 6;

    float2 ml[NSPLIT];
    float M = -__builtin_inff();
#pragma unroll
    for (int s = 0; s < NSPLIT; ++s) {
        ml[s] = Ml[((size_t)s * NHEAD + h) * NTOK + row];
        M = fmaxf(M, ml[s].x);
    }
    float denom = 0.f;
    float4 acc = make_float4(0.f, 0.f, 0.f, 0.f);
#pragma unroll
    for (int s = 0; s < NSPLIT; ++s) {
        float w = exp2f(ml[s].x - M);
        denom += w * ml[s].y;
        float4 ov = *reinterpret_cast<const float4*>(
            Opart + ((size_t)s * NTOK + row) * 512 + c4);
        acc.x += w * ov.x; acc.y += w * ov.y;
        acc.z += w * ov.z; acc.w += w * ov.w;
    }
    float inv = 1.f / denom;
    __bf16* op = O + (size_t)row * 512 + c4;
    op[0] = (__bf16)(acc.x * inv); op[1] = (__bf16)(acc.y * inv);
    op[2] = (__bf16)(acc.z * inv); op[3] = (__bf16)(acc.w * inv);
}

// ============================================================
// Kernel 3: output projection. O[4096,512] bf16 @ Wout[512,256] fp32 + bias
// ============================================================
__global__ __launch_bounds__(256) void gemm_out_k(
    const __bf16* __restrict__ O, const float* __restrict__ W,
    const float* __restrict__ bias, float* __restrict__ out)
{
    __shared__ __bf16 As[64 * 40];
    __shared__ __bf16 Bs[64 * 40];
    const int tid  = threadIdx.x;
    const int lane = tid & 63;
    const int wv   = tid >> 6;
    const int wr   = wv >> 1, wc = wv & 1;
    const int m0 = blockIdx.y * 64;
    const int n0 = blockIdx.x * 64;
    const int l15 = lane & 15, l4 = lane >> 4;

    f32x4 zero = {0.f, 0.f, 0.f, 0.f};
    f32x4 acc[2][2];
#pragma unroll
    for (int i = 0; i < 2; ++i)
#pragma unroll
        for (int j = 0; j < 2; ++j) acc[i][j] = zero;

    for (int k0 = 0; k0 < 512; k0 += 32) {
        __syncthreads();
        {
            int row = tid >> 2, c8 = tid & 3;
            *reinterpret_cast<bfx8*>(&As[row * 40 + c8 * 8]) =
                *reinterpret_cast<const bfx8*>(O + (size_t)(m0 + row) * 512 + k0 + c8 * 8);
        }
#pragma unroll
        for (int rep = 0; rep < 2; ++rep) {
            int idx = rep * 256 + tid;
            int kk = idx >> 4, n4 = idx & 15;
            float4 v = *reinterpret_cast<const float4*>(
                W + (size_t)(k0 + kk) * 256 + n0 + n4 * 4);
            Bs[(n4 * 4 + 0) * 40 + kk] = (__bf16)v.x;
            Bs[(n4 * 4 + 1) * 40 + kk] = (__bf16)v.y;
            Bs[(n4 * 4 + 2) * 40 + kk] = (__bf16)v.z;
            Bs[(n4 * 4 + 3) * 40 + kk] = (__bf16)v.w;
        }
        __syncthreads();

        bfx8 af[2], bfr[2];
#pragma unroll
        for (int m = 0; m < 2; ++m)
            af[m] = *reinterpret_cast<const bfx8*>(
                &As[(wr * 32 + m * 16 + l15) * 40 + l4 * 8]);
#pragma unroll
        for (int n = 0; n < 2; ++n)
            bfr[n] = *reinterpret_cast<const bfx8*>(
                &Bs[(wc * 32 + n * 16 + l15) * 40 + l4 * 8]);
#pragma unroll
        for (int m = 0; m < 2; ++m)
#pragma unroll
            for (int n = 0; n < 2; ++n)
                acc[m][n] = mfma16(af[m], bfr[n], acc[m][n]);
    }

#pragma unroll
    for (int m = 0; m < 2; ++m)
#pragma unroll
        for (int n = 0; n < 2; ++n)
#pragma unroll
            for (int r = 0; r < 4; ++r) {
                int row = m0 + wr * 32 + m * 16 + l4 * 4 + r;
                int col = n0 + wc * 32 + n * 16 + l15;
                out[(size_t)row * 256 + col] = acc[m][n][r] + bias[col];
            }
}

// ============================================================
extern "C" void kernel_launch(void* const* d_in, const int* in_sizes, int n_in,
                              void* d_out, int out_size, void* d_ws, size_t ws_size,
                              hipStream_t stream) {
    const float* x     = (const float*)d_in[0];
    const float* w_qkv = (const float*)d_in[1];
    const float* w_out = (const float*)d_in[2];
    const float* b_out = (const float*)d_in[3];
    float* out = (float*)d_out;

    __bf16* Q  = (__bf16*)d_ws;
    __bf16* K  = Q  + (size_t)NHEAD * NTOK * DHEAD;
    __bf16* Vt = K  + (size_t)NHEAD * NTOK * DHEAD;
    __bf16* O  = Vt + (size_t)NHEAD * NTOK * DHEAD;
    float*  Opart = (float*)(O + (size_t)NTOK * 512);
    float2* Ml    = (float2*)(Opart + (size_t)NSPLIT * NTOK * 512);

    gemm_qkv    <<<dim3(12, 32), 256, 0, stream>>>(x, w_qkv, Q, K, Vt);
    attn_fwd    <<<dim3((NTOK / 64) * NSPLIT * NHEAD), 256, 0, stream>>>(Q, K, Vt, Opart, Ml);
    attn_combine<<<dim3(NTOK * 128 / 256), 256, 0, stream>>>(Opart, Ml, O);
    gemm_out_k  <<<dim3(256 / 64, NTOK / 64), 256, 0, stream>>>(O, w_out, b_out, out);
}

// Round 5
// 116.372 us; speedup vs baseline: 2.9060x; 1.1435x over previous
//
#include <hip/hip_runtime.h>
#include <hip/hip_bf16.h>

// ---------- types ----------
typedef float f32x4  __attribute__((ext_vector_type(4)));
typedef float f32x16 __attribute__((ext_vector_type(16)));
typedef __bf16 bfx8  __attribute__((ext_vector_type(8)));

#define NTOK 4096
#define NHEAD 8
#define DHEAD 64
#define NSPLIT 2
#define KCHUNK (NTOK / NSPLIT)

__device__ inline f32x4 mfma16(bfx8 a, bfx8 b, f32x4 c) {
    return __builtin_amdgcn_mfma_f32_16x16x32_bf16(a, b, c, 0, 0, 0);
}
__device__ inline f32x16 mfma32(bfx8 a, bfx8 b, f32x16 c) {
    return __builtin_amdgcn_mfma_f32_32x32x16_bf16(a, b, c, 0, 0, 0);
}

__device__ __forceinline__ void gld_lds16(const __bf16* g, __bf16* lds) {
    __builtin_amdgcn_global_load_lds(
        (const __attribute__((address_space(1))) void*)g,
        (__attribute__((address_space(3))) void*)lds, 16, 0, 0);
}

// ============================================================
// Kernel 1: QKV projection. X[4096,256] fp32 @ W[256,1536] fp32
//  -> Q[h][n][64] bf16 (x 0.125*log2e), K[h][n][64] bf16, Vt[h][64][n] bf16
// ============================================================
__global__ __launch_bounds__(256) void gemm_qkv(
    const float* __restrict__ X, const float* __restrict__ W,
    __bf16* __restrict__ Q, __bf16* __restrict__ Kb, __bf16* __restrict__ Vt)
{
    __shared__ __bf16 As[128 * 40];
    __shared__ __bf16 Bs[128 * 40];
    const int tid  = threadIdx.x;
    const int lane = tid & 63;
    const int wv   = tid >> 6;
    const int wr   = wv >> 1, wc = wv & 1;
    const int m0 = blockIdx.y * 128;
    const int n0 = blockIdx.x * 128;
    const int l15 = lane & 15, l4 = lane >> 4;

    f32x4 zero = {0.f, 0.f, 0.f, 0.f};
    f32x4 acc[4][4];
#pragma unroll
    for (int i = 0; i < 4; ++i)
#pragma unroll
        for (int j = 0; j < 4; ++j) acc[i][j] = zero;

    for (int k0 = 0; k0 < 256; k0 += 32) {
        __syncthreads();
#pragma unroll
        for (int rep = 0; rep < 4; ++rep) {
            int idx = rep * 256 + tid;
            int row = idx >> 3, c4 = idx & 7;
            float4 v = *reinterpret_cast<const float4*>(
                X + (size_t)(m0 + row) * 256 + k0 + c4 * 4);
            __bf16* p = &As[row * 40 + c4 * 4];
            p[0] = (__bf16)v.x; p[1] = (__bf16)v.y;
            p[2] = (__bf16)v.z; p[3] = (__bf16)v.w;
        }
#pragma unroll
        for (int rep = 0; rep < 4; ++rep) {
            int idx = rep * 256 + tid;
            int kk = idx >> 5, n4 = idx & 31;
            float4 v = *reinterpret_cast<const float4*>(
                W + (size_t)(k0 + kk) * 1536 + n0 + n4 * 4);
            Bs[(n4 * 4 + 0) * 40 + kk] = (__bf16)v.x;
            Bs[(n4 * 4 + 1) * 40 + kk] = (__bf16)v.y;
            Bs[(n4 * 4 + 2) * 40 + kk] = (__bf16)v.z;
            Bs[(n4 * 4 + 3) * 40 + kk] = (__bf16)v.w;
        }
        __syncthreads();

        bfx8 af[4], bfr[4];
#pragma unroll
        for (int m = 0; m < 4; ++m)
            af[m] = *reinterpret_cast<const bfx8*>(
                &As[(wr * 64 + m * 16 + l15) * 40 + l4 * 8]);
#pragma unroll
        for (int n = 0; n < 4; ++n)
            bfr[n] = *reinterpret_cast<const bfx8*>(
                &Bs[(wc * 64 + n * 16 + l15) * 40 + l4 * 8]);
#pragma unroll
        for (int m = 0; m < 4; ++m)
#pragma unroll
            for (int n = 0; n < 4; ++n)
                acc[m][n] = mfma16(af[m], bfr[n], acc[m][n]);
    }

    const float QSCALE = 0.125f * 1.44269504088896f;
#pragma unroll
    for (int m = 0; m < 4; ++m)
#pragma unroll
        for (int n = 0; n < 4; ++n)
#pragma unroll
            for (int r = 0; r < 4; ++r) {
                int row = m0 + wr * 64 + m * 16 + l4 * 4 + r;
                int f   = n0 + wc * 64 + n * 16 + l15;
                float v = acc[m][n][r];
                if (f < 512) {
                    Q[(size_t)(f >> 6) * (NTOK * DHEAD) + (size_t)row * DHEAD + (f & 63)] =
                        (__bf16)(v * QSCALE);
                } else if (f < 1024) {
                    int g = f - 512;
                    Kb[(size_t)(g >> 6) * (NTOK * DHEAD) + (size_t)row * DHEAD + (g & 63)] =
                        (__bf16)v;
                } else {
                    int g = f - 1024;
                    Vt[(size_t)(g >> 6) * (DHEAD * NTOK) + (size_t)(g & 63) * NTOK + row] =
                        (__bf16)v;
                }
            }
}

// ============================================================
// Kernel 2: flash attention, 8 waves x 32 q-rows, 32x32x16 MFMA.
// Swapped QK^T: lane owns q=l&31, 16 of 32 keys (partner lane l^32 has rest)
// -> softmax reduce = 15 fmax + 1 shfl_xor(32). Logits in log2 units.
// K/V staged in LDS (XOR-swizzled, double-buffered), shared by 8 waves.
// KV-split x2, flat grid bid%8 == head for XCD L2 pinning.
// ============================================================
__global__ __launch_bounds__(512) void attn_fwd(
    const __bf16* __restrict__ Q, const __bf16* __restrict__ Kb,
    const __bf16* __restrict__ Vt,
    float* __restrict__ Opart, float2* __restrict__ Ml)
{
    const int tid  = threadIdx.x;
    const int lane = tid & 63;
    const int wv   = tid >> 6;          // 0..7
    const int bid = blockIdx.x;
    const int h  = bid & 7;
    const int t2 = bid >> 3;
    const int sp = t2 & 1;
    const int qb = t2 >> 1;             // 0..15
    const int l31 = lane & 31;
    const int hi  = lane >> 5;

    const __bf16* Qh = Q  + (size_t)h * NTOK * DHEAD;
    const __bf16* Kh = Kb + (size_t)h * NTOK * DHEAD;
    const __bf16* Vh = Vt + (size_t)h * DHEAD * NTOK;

    __shared__ __bf16 Ks[2][64 * 64];     // 8 KB x2
    __shared__ __bf16 Vs[2][64 * 64];     // 8 KB x2
    __shared__ __bf16 Plds[8][32 * 64];   // per-wave 4 KB P buffer
    char* Pw = reinterpret_cast<char*>(&Plds[wv][0]);

    const int srow  = tid >> 3;                 // 0..63
    const int scol8 = (tid & 7) ^ (srow & 7);   // pre-swizzled source col group

    const int qrow = qb * 256 + wv * 32 + l31;
    bfx8 qf[4];
#pragma unroll
    for (int s = 0; s < 4; ++s)
        qf[s] = *reinterpret_cast<const bfx8*>(
            Qh + (size_t)qrow * DHEAD + s * 16 + hi * 8);

    f32x16 o0, o1;
#pragma unroll
    for (int r = 0; r < 16; ++r) { o0[r] = 0.f; o1[r] = 0.f; }
    float m_l = -__builtin_inff();
    float l_l = 0.f;

    const int jbeg = sp * KCHUNK, jend = jbeg + KCHUNK;
    const int ksw = (l31 & 7) << 4;

    auto stage = [&](int bf, int j0) {
        gld_lds16(Kh + (size_t)(j0 + srow) * DHEAD + scol8 * 8, &Ks[bf][wv * 8 * 64]);
        gld_lds16(Vh + (size_t)srow * NTOK + j0 + scol8 * 8,    &Vs[bf][wv * 8 * 64]);
    };

    stage(0, jbeg);
    __syncthreads();

    int buf = 0;
    for (int j0 = jbeg; j0 < jend; j0 += 64) {
        if (j0 + 64 < jend) stage(buf ^ 1, j0 + 64);

        const char* Kt  = reinterpret_cast<const char*>(&Ks[buf][0]);
        const char* Vtc = reinterpret_cast<const char*>(&Vs[buf][0]);

#pragma unroll
        for (int kb = 0; kb < 2; ++kb) {
            // ---- S' = K Q^T : lane holds S[key(r,hi)][q=l31] ----
            const char* Kr = Kt + (kb * 32 + l31) * 128;
            f32x16 sa;
#pragma unroll
            for (int r = 0; r < 16; ++r) sa[r] = 0.f;
            __builtin_amdgcn_s_setprio(1);
#pragma unroll
            for (int s = 0; s < 4; ++s) {
                bfx8 kf = *reinterpret_cast<const bfx8*>(Kr + (((s * 2 + hi) * 16) ^ ksw));
                sa = mfma32(kf, qf[s], sa);
            }
            __builtin_amdgcn_s_setprio(0);

            // ---- row max: 15 in-reg fmax + 1 cross-half shuffle ----
            float tm = fmaxf(fmaxf(fmaxf(sa[0], sa[1]), fmaxf(sa[2], sa[3])),
                             fmaxf(fmaxf(sa[4], sa[5]), fmaxf(sa[6], sa[7])));
            tm = fmaxf(tm,
                 fmaxf(fmaxf(fmaxf(sa[8], sa[9]),  fmaxf(sa[10], sa[11])),
                       fmaxf(fmaxf(sa[12], sa[13]), fmaxf(sa[14], sa[15]))));
            tm = fmaxf(tm, __shfl_xor(tm, 32, 64));

            // ---- defer-rescale (T13): THR = 8 nats = 11.54 log2 ----
            if (__ballot(tm > m_l + 11.5416f)) {
                float mnew = fmaxf(m_l, tm);
                float corr = __builtin_amdgcn_exp2f(m_l - mnew);
                m_l = mnew;
                l_l *= corr;
#pragma unroll
                for (int r = 0; r < 16; ++r) {
                    float cr = __shfl(corr, (r & 3) + 8 * (r >> 2) + 4 * hi, 64);
                    o0[r] *= cr; o1[r] *= cr;
                }
            }

            // ---- P = exp2(S - m): 16 v_exp; pack 4 bf16 -> ds_write_b64 ----
            float ps = 0.f;
#pragma unroll
            for (int g = 0; g < 4; ++g) {
                float p0 = __builtin_amdgcn_exp2f(sa[g * 4 + 0] - m_l);
                float p1 = __builtin_amdgcn_exp2f(sa[g * 4 + 1] - m_l);
                float p2 = __builtin_amdgcn_exp2f(sa[g * 4 + 2] - m_l);
                float p3 = __builtin_amdgcn_exp2f(sa[g * 4 + 3] - m_l);
                ps += (p0 + p1) + (p2 + p3);
                union { __bf16 hh[4]; int2 v; } u;
                u.hh[0] = (__bf16)p0; u.hh[1] = (__bf16)p1;
                u.hh[2] = (__bf16)p2; u.hh[3] = (__bf16)p3;
                // key base = kb*32 + g*8 + hi*4 -> byte = kb*64 + g*16 + hi*8
                int byte = (l31 * 128 + kb * 64 + g * 16 + hi * 8) ^ ksw;
                *reinterpret_cast<int2*>(Pw + byte) = u.v;
            }
            ps += __shfl_xor(ps, 32, 64);
            l_l += ps;

            __builtin_amdgcn_wave_barrier();   // same-wave P write->read order

            // ---- O += P V for this 32-key block ----
            __builtin_amdgcn_s_setprio(1);
#pragma unroll
            for (int s2 = 0; s2 < 2; ++s2) {
                int colb = (kb * 64 + s2 * 32 + hi * 16);
                bfx8 pf = *reinterpret_cast<const bfx8*>(
                    Pw + ((l31 * 128 + colb) ^ ksw));
                bfx8 vf0 = *reinterpret_cast<const bfx8*>(
                    Vtc + l31 * 128 + (colb ^ ksw));
                o0 = mfma32(pf, vf0, o0);
                bfx8 vf1 = *reinterpret_cast<const bfx8*>(
                    Vtc + (32 + l31) * 128 + (colb ^ ksw));
                o1 = mfma32(pf, vf1, o1);
            }
            __builtin_amdgcn_s_setprio(0);
        }

        __syncthreads();   // staged buf^1 complete; reads of buf done
        buf ^= 1;
    }

    // ---- store unnormalized partial O (fp32) + per-row (m, l) ----
#pragma unroll
    for (int r = 0; r < 16; ++r) {
        int q = (r & 3) + 8 * (r >> 2) + 4 * hi;
        size_t row = (size_t)(qb * 256 + wv * 32 + q);
        float* dst = Opart + ((size_t)sp * NTOK + row) * 512 + h * 64 + l31;
        dst[0]  = o0[r];
        dst[32] = o1[r];
    }
    if (hi == 0) {
        Ml[((size_t)sp * NHEAD + h) * NTOK + qrow] = make_float2(m_l, l_l);
    }
}

// ============================================================
// Kernel 2b: combine NSPLIT partials -> O bf16 [4096][512]
// (m in log2 units: weights = exp2(m - M))
// ============================================================
__global__ __launch_bounds__(256) void attn_combine(
    const float* __restrict__ Opart, const float2* __restrict__ Ml,
    __bf16* __restrict__ O)
{
    int idx = blockIdx.x * 256 + threadIdx.x;      // 4096 * 128
    int row = idx >> 7;
    int c4  = (idx & 127) * 4;
    int h   = c4 >> 6;

    float2 ml[NSPLIT];
    float M = -__builtin_inff();
#pragma unroll
    for (int s = 0; s < NSPLIT; ++s) {
        ml[s] = Ml[((size_t)s * NHEAD + h) * NTOK + row];
        M = fmaxf(M, ml[s].x);
    }
    float denom = 0.f;
    float4 acc = make_float4(0.f, 0.f, 0.f, 0.f);
#pragma unroll
    for (int s = 0; s < NSPLIT; ++s) {
        float w = exp2f(ml[s].x - M);
        denom += w * ml[s].y;
        float4 ov = *reinterpret_cast<const float4*>(
            Opart + ((size_t)s * NTOK + row) * 512 + c4);
        acc.x += w * ov.x; acc.y += w * ov.y;
        acc.z += w * ov.z; acc.w += w * ov.w;
    }
    float inv = 1.f / denom;
    __bf16* op = O + (size_t)row * 512 + c4;
    op[0] = (__bf16)(acc.x * inv); op[1] = (__bf16)(acc.y * inv);
    op[2] = (__bf16)(acc.z * inv); op[3] = (__bf16)(acc.w * inv);
}

// ============================================================
// Kernel 3: output projection. O[4096,512] bf16 @ Wout[512,256] fp32 + bias
// ============================================================
__global__ __launch_bounds__(256) void gemm_out_k(
    const __bf16* __restrict__ O, const float* __restrict__ W,
    const float* __restrict__ bias, float* __restrict__ out)
{
    __shared__ __bf16 As[64 * 40];
    __shared__ __bf16 Bs[64 * 40];
    const int tid  = threadIdx.x;
    const int lane = tid & 63;
    const int wv   = tid >> 6;
    const int wr   = wv >> 1, wc = wv & 1;
    const int m0 = blockIdx.y * 64;
    const int n0 = blockIdx.x * 64;
    const int l15 = lane & 15, l4 = lane >> 4;

    f32x4 zero = {0.f, 0.f, 0.f, 0.f};
    f32x4 acc[2][2];
#pragma unroll
    for (int i = 0; i < 2; ++i)
#pragma unroll
        for (int j = 0; j < 2; ++j) acc[i][j] = zero;

    for (int k0 = 0; k0 < 512; k0 += 32) {
        __syncthreads();
        {
            int row = tid >> 2, c8 = tid & 3;
            *reinterpret_cast<bfx8*>(&As[row * 40 + c8 * 8]) =
                *reinterpret_cast<const bfx8*>(O + (size_t)(m0 + row) * 512 + k0 + c8 * 8);
        }
#pragma unroll
        for (int rep = 0; rep < 2; ++rep) {
            int idx = rep * 256 + tid;
            int kk = idx >> 4, n4 = idx & 15;
            float4 v = *reinterpret_cast<const float4*>(
                W + (size_t)(k0 + kk) * 256 + n0 + n4 * 4);
            Bs[(n4 * 4 + 0) * 40 + kk] = (__bf16)v.x;
            Bs[(n4 * 4 + 1) * 40 + kk] = (__bf16)v.y;
            Bs[(n4 * 4 + 2) * 40 + kk] = (__bf16)v.z;
            Bs[(n4 * 4 + 3) * 40 + kk] = (__bf16)v.w;
        }
        __syncthreads();

        bfx8 af[2], bfr[2];
#pragma unroll
        for (int m = 0; m < 2; ++m)
            af[m] = *reinterpret_cast<const bfx8*>(
                &As[(wr * 32 + m * 16 + l15) * 40 + l4 * 8]);
#pragma unroll
        for (int n = 0; n < 2; ++n)
            bfr[n] = *reinterpret_cast<const bfx8*>(
                &Bs[(wc * 32 + n * 16 + l15) * 40 + l4 * 8]);
#pragma unroll
        for (int m = 0; m < 2; ++m)
#pragma unroll
            for (int n = 0; n < 2; ++n)
                acc[m][n] = mfma16(af[m], bfr[n], acc[m][n]);
    }

#pragma unroll
    for (int m = 0; m < 2; ++m)
#pragma unroll
        for (int n = 0; n < 2; ++n)
#pragma unroll
            for (int r = 0; r < 4; ++r) {
                int row = m0 + wr * 32 + m * 16 + l4 * 4 + r;
                int col = n0 + wc * 32 + n * 16 + l15;
                out[(size_t)row * 256 + col] = acc[m][n][r] + bias[col];
            }
}

// ============================================================
extern "C" void kernel_launch(void* const* d_in, const int* in_sizes, int n_in,
                              void* d_out, int out_size, void* d_ws, size_t ws_size,
                              hipStream_t stream) {
    const float* x     = (const float*)d_in[0];
    const float* w_qkv = (const float*)d_in[1];
    const float* w_out = (const float*)d_in[2];
    const float* b_out = (const float*)d_in[3];
    float* out = (float*)d_out;

    __bf16* Q  = (__bf16*)d_ws;
    __bf16* K  = Q  + (size_t)NHEAD * NTOK * DHEAD;
    __bf16* Vt = K  + (size_t)NHEAD * NTOK * DHEAD;
    __bf16* O  = Vt + (size_t)NHEAD * NTOK * DHEAD;
    float*  Opart = (float*)(O + (size_t)NTOK * 512);
    float2* Ml    = (float2*)(Opart + (size_t)NSPLIT * NTOK * 512);

    gemm_qkv    <<<dim3(12, 32), 256, 0, stream>>>(x, w_qkv, Q, K, Vt);
    // flat grid: bid%8 == head; 16 qb x 2 sp x 8 h = 256 blocks of 512 thr
    attn_fwd    <<<dim3((NTOK / 256) * NSPLIT * NHEAD), 512, 0, stream>>>(Q, K, Vt, Opart, Ml);
    attn_combine<<<dim3(NTOK * 128 / 256), 256, 0, stream>>>(Opart, Ml, O);
    gemm_out_k  <<<dim3(256 / 64, NTOK / 64), 256, 0, stream>>>(O, w_out, b_out, out);
}